// Round 8
// baseline (162.577 us; speedup 1.0000x reference)
//
#include <hip/hip_runtime.h>

// MSA conv2d-like QK correlation:
// out[b, i*3+j, h, w] = sum_c Q[b,c,h,w] * K[b,c,h+i-1,w+j-1]  (zero-padded)
// B=8, C=128, H=W=128, fp32.
//
// Round 8 (= R6/R7 resubmit; neither ran - infra failures).
// R2-R5 (scalar, vector, 4x waves, async global_load_lds+vmcnt pipeline)
// ALL pin at ~55us / ~2.3 TB/s effective with every pipe idle. Model:
// per-CU miss throughput = MSHR_slots / per-miss-latency; compulsory
// 8192 lines/CU at ~860ns -> 55us regardless of structure. Copy ubench
// (6.3 TB/s) fits the same cap at ~350ns/miss: sequential streams get DRAM
// row locality, our 1-4KB fragments at 64KB stride (x2048 scattered blocks)
// do not. Lever: instantaneous address DENSITY.
// Fix: block = 1024 thr = (b, 32-row strip); per c the block reads Q 16KB +
// K 17KB dense (8x fewer, 8x longer streams than R4). Inner loop = R4's
// float4+shfl form (4 aligned dwordx4/thread-c), unroll 4. CSPLIT=8
// partials in ws + 8-way reduce; atomic fallback if ws too small.

#define Bn 8
#define Cn 128
#define Hn 128
#define Wn 128
#define HWn (Hn * Wn)
#define ROWS 32                // rows per block strip
#define CSPLIT 8
#define CCHUNK (Cn / CSPLIT)   // 16 channels per block
#define OUTN (Bn * 9 * HWn)    // 1179648 output elements

template <bool ATOMIC>
__global__ __launch_bounds__(1024) void msa_conv_v6(
    const float* __restrict__ Q, const float* __restrict__ K,
    float* __restrict__ dst) {
  const int idx = threadIdx.x;   // 0..1023
  const int wq  = idx & 31;      // float4 column; w0 = 4*wq
  const int rr  = idx >> 5;      // row within strip 0..31
  const int w0  = wq * 4;
  const int r   = blockIdx.x * ROWS + rr;  // output row
  const int b   = blockIdx.y;
  const int cs  = blockIdx.z;

  // Mirror-clamped neighbor rows (OOB rows -> in-bounds dummy; taps zeroed
  // in the epilogue). All addresses stay inside the allocation.
  const int rm = (r > 0) ? r - 1 : r + 1;
  const int rp = (r < Hn - 1) ? r + 1 : r - 1;

  const size_t base = ((size_t)b * Cn + (size_t)cs * CCHUNK) * HWn;
  const float* qp = Q + base + (size_t)r  * Wn + w0;
  const float* mp = K + base + (size_t)rm * Wn + w0;
  const float* zp = K + base + (size_t)r  * Wn + w0;
  const float* pp = K + base + (size_t)rp * Wn + w0;

  float acc[9][4] = {};

#define ACC4(t, s0, s1, s2, s3) \
  acc[t][0] += q4.x * (s0);     \
  acc[t][1] += q4.y * (s1);     \
  acc[t][2] += q4.z * (s2);     \
  acc[t][3] += q4.w * (s3);

#pragma unroll 4
  for (int c = 0; c < CCHUNK; ++c) {
    const float4 q4 = *(const float4*)qp;
    const float4 m4 = *(const float4*)mp;
    const float4 z4 = *(const float4*)zp;
    const float4 p4 = *(const float4*)pp;
    // Wave = 2 rows x 32 wq (lane bit5 = row parity), so +-1-lane shuffles
    // move along w within a row; wq==0 / wq==31 receive garbage -- exactly
    // the components masked in the epilogue.
    const float mL = __shfl_up(m4.w, 1, 64);
    const float zL = __shfl_up(z4.w, 1, 64);
    const float pL = __shfl_up(p4.w, 1, 64);
    const float mR = __shfl_down(m4.x, 1, 64);
    const float zR = __shfl_down(z4.x, 1, 64);
    const float pR = __shfl_down(p4.x, 1, 64);

    ACC4(0, mL,   m4.x, m4.y, m4.z)   // i=-1, j=-1
    ACC4(1, m4.x, m4.y, m4.z, m4.w)   // i=-1, j= 0
    ACC4(2, m4.y, m4.z, m4.w, mR)     // i=-1, j=+1
    ACC4(3, zL,   z4.x, z4.y, z4.z)   // i= 0, j=-1
    ACC4(4, z4.x, z4.y, z4.z, z4.w)   // i= 0, j= 0
    ACC4(5, z4.y, z4.z, z4.w, zR)     // i= 0, j=+1
    ACC4(6, pL,   p4.x, p4.y, p4.z)   // i=+1, j=-1
    ACC4(7, p4.x, p4.y, p4.z, p4.w)   // i=+1, j= 0
    ACC4(8, p4.y, p4.z, p4.w, pR)     // i=+1, j=+1

    qp += HWn; mp += HWn; zp += HWn; pp += HWn;
  }
#undef ACC4

  // Epilogue masking: OOB taps/components have fully-zero C-sums in the
  // reference (zero padding), so zero them here.
  if (wq == 0)  { acc[0][0] = 0.f; acc[3][0] = 0.f; acc[6][0] = 0.f; }
  if (wq == 31) { acc[2][3] = 0.f; acc[5][3] = 0.f; acc[8][3] = 0.f; }
  if (r == 0) {
#pragma unroll
    for (int t = 0; t < 3; ++t)
#pragma unroll
      for (int k = 0; k < 4; ++k) acc[t][k] = 0.f;
  }
  if (r == Hn - 1) {
#pragma unroll
    for (int t = 6; t < 9; ++t)
#pragma unroll
      for (int k = 0; k < 4; ++k) acc[t][k] = 0.f;
  }

  const size_t o = (size_t)b * 9 * HWn + (size_t)r * Wn + w0;
  if (ATOMIC) {
#pragma unroll
    for (int t = 0; t < 9; ++t)
#pragma unroll
      for (int k = 0; k < 4; ++k)
        atomicAdd(dst + o + (size_t)t * HWn + k, acc[t][k]);
  } else {
    float* p = dst + (size_t)cs * OUTN + o;
#pragma unroll
    for (int t = 0; t < 9; ++t)
      *(float4*)(p + (size_t)t * HWn) =
          make_float4(acc[t][0], acc[t][1], acc[t][2], acc[t][3]);
  }
}

// out[i] = sum_{cs<8} part[cs*OUTN + i], float4-wide.
__global__ __launch_bounds__(256) void msa_reduce8(
    const float* __restrict__ part, float* __restrict__ out) {
  const int i = blockIdx.x * 256 + threadIdx.x;  // float4 index
  const int n4 = OUTN / 4;
  const float4* p = (const float4*)part;
  float4 s = p[i];
#pragma unroll
  for (int cs = 1; cs < CSPLIT; ++cs) {
    const float4 v = p[(size_t)cs * n4 + i];
    s.x += v.x; s.y += v.y; s.z += v.z; s.w += v.w;
  }
  ((float4*)out)[i] = s;
}

__global__ __launch_bounds__(256) void msa_zero(float* __restrict__ out) {
  const int i = blockIdx.x * 256 + threadIdx.x;
  ((float4*)out)[i] = make_float4(0.f, 0.f, 0.f, 0.f);
}

extern "C" void kernel_launch(void* const* d_in, const int* in_sizes, int n_in,
                              void* d_out, int out_size, void* d_ws,
                              size_t ws_size, hipStream_t stream) {
  const float* Q = (const float*)d_in[0];
  const float* K = (const float*)d_in[1];
  float* out = (float*)d_out;

  dim3 block(1024);
  dim3 grid(Hn / ROWS, Bn, CSPLIT);  // 4 x 8 x 8 = 256 blocks, 1/CU

  const size_t ws_need = (size_t)CSPLIT * OUTN * sizeof(float);  // 37.7 MB
  if (ws_size >= ws_need) {
    float* part = (float*)d_ws;
    msa_conv_v6<false><<<grid, block, 0, stream>>>(Q, K, part);
    msa_reduce8<<<OUTN / 4 / 256, 256, 0, stream>>>(part, out);
  } else {
    msa_zero<<<OUTN / 4 / 256, 256, 0, stream>>>(out);
    msa_conv_v6<true><<<grid, block, 0, stream>>>(Q, K, out);
  }
}